// Round 14
// baseline (125.427 us; speedup 1.0000x reference)
//
#include <hip/hip_runtime.h>
#include <math.h>

#define BATCH 128
#define DIM   8192
#define HW    49
#define PAIRS 2401            // 49*49
#define SLOT  2512            // per-partial slot: 2401 G + 49 nA + 49 nB + pad

// ws float offsets
#define WS_MSE    0
#define WS_VARA   1
#define WS_VARB   2
#define WS_DIAGA  3
#define WS_DIAGB  4
#define WS_S1     5
#define WS_S2     6
#define WS_S3     7
#define WS_S4     8
#define WS_SK2A   9
#define WS_SK2B   10
#define WS_TICKET 11
#define COLS_OFF    16                         // saA,qaA,sbB,qbB: 4*DIM
#define GRAMA_OFF   32784
#define GRAMB_OFF   49168
#define GK2PART_OFF 65552                      // 64 chunks * 32768 (A then B)
#define L1PART_BIG  2162704                    // 256 slots * SLOT
#define WS_NEED_FLOATS (L1PART_BIG + 256 * SLOT)    // ~11.2 MB
#define L1PART_SMALL 65552                     // fallback: 128 batch slots (atomic)

typedef __attribute__((ext_vector_type(8))) short bf16x8;
typedef __attribute__((ext_vector_type(4))) float f32x4;

__device__ __forceinline__ unsigned cvtpk(float lo, float hi) {
    unsigned r;
    asm("v_cvt_pk_bf16_f32 %0, %1, %2" : "=v"(r) : "v"(lo), "v"(hi));
    return r;
}

#define SB0() __builtin_amdgcn_sched_barrier(0)

// ---------------------------------------------------------------------------
// UBER kernel, 512 threads, grid = 256 (1 block/CU; LDS 98KB forces it).
// L1 role: DRAM-page-locality design — ONE WAVE reads ONE ROW-TOUCH of 1KB
// CONTIGUOUS per unit (BK=256 fp32), 98 row-units/stage, 16 stages (K=4096
// per block). Staging via the VGPR path with manual inline-asm loads (compiler
// cannot sink or auto-drain), 2 register sets (stages s, s+1 in flight),
// per-wave counted s_waitcnt vmcnt(13/12), cvt fp32->bf16 in-register,
// swizzled ds_write into 2 x 49KB bf16 LDS buffers, raw s_barrier (no
// __syncthreads in the loop — it would emit vmcnt(0) and drain the pipe).
// Per-CU fill model: BW = outstanding-capacity(~5KB, MSHR) / latency; 1KB
// temporally-adjacent touches maximize DRAM open-page hits -> lower latency.
// Row norms from MFMA diagonals. Blocks 0..63 run the GK2 prologue first
// (z_a/z_b Grams + col stats + MSE), then vmcnt(0) re-zeroes the counter.
// ---------------------------------------------------------------------------
template<bool RED>
__global__ __launch_bounds__(512) void uber(const float* __restrict__ za_l,
                                            const float* __restrict__ zb_l,
                                            const float* __restrict__ z_a,
                                            const float* __restrict__ z_b,
                                            float* __restrict__ ws,
                                            float* __restrict__ l1part)
{
    __shared__ __align__(16) unsigned char shm[100352];   // gk2 needs 77824
    const int tid = threadIdx.x;

    if (blockIdx.x < 64) {
        // ================= GK2 prologue (both tensors + col stats + MSE) =====
        const int chunk = blockIdx.x;
        float* sxA = (float*)shm;                 // 128*68
        float* sxB = sxA + 128 * 68;
        float* scr = sxB + 128 * 68;              // 2048-float scratch
        const int ty = tid >> 5, tx = tid & 31;
        const int q = tid >> 6, cc = tid & 63;

        float accA[8][4], accB[8][4];
#pragma unroll
        for (int r = 0; r < 8; ++r)
#pragma unroll
            for (int c = 0; c < 4; ++c) { accA[r][c] = 0.f; accB[r][c] = 0.f; }
        float cSA[2] = {0.f,0.f}, cQA[2] = {0.f,0.f};
        float cSB[2] = {0.f,0.f}, cQB[2] = {0.f,0.f};
        float mse = 0.f;

#pragma unroll
        for (int st = 0; st < 2; ++st) {
            __syncthreads();
            for (int f = tid; f < 2048; f += 512) {
                int row = f >> 4, c4 = f & 15;
                const float4 a4 = *(const float4*)(z_a + (size_t)row * DIM + chunk * 128 + st * 64 + c4 * 4);
                const float4 b4 = *(const float4*)(z_b + (size_t)row * DIM + chunk * 128 + st * 64 + c4 * 4);
                *(float4*)(sxA + row * 68 + c4 * 4) = a4;
                *(float4*)(sxB + row * 68 + c4 * 4) = b4;
                float dx = a4.x - b4.x, dy = a4.y - b4.y, dz = a4.z - b4.z, dw = a4.w - b4.w;
                mse += dx * dx + dy * dy + dz * dz + dw * dw;
            }
            __syncthreads();
            for (int r = 0; r < 16; ++r) {
                float vA = sxA[(q * 16 + r) * 68 + cc];
                float vB = sxB[(q * 16 + r) * 68 + cc];
                cSA[st] += vA; cQA[st] += vA * vA;
                cSB[st] += vB; cQB[st] += vB * vB;
            }
            for (int k = 0; k < 64; k += 4) {
                float4 ar4[8], br4[8];
#pragma unroll
                for (int r = 0; r < 8; ++r) {
                    ar4[r] = *(const float4*)(sxA + (ty + 16 * r) * 68 + k);
                    br4[r] = *(const float4*)(sxB + (ty + 16 * r) * 68 + k);
                }
#pragma unroll
                for (int c = 0; c < 4; ++c) {
                    float4 ac4 = *(const float4*)(sxA + (tx + 32 * c) * 68 + k);
                    float4 bc4 = *(const float4*)(sxB + (tx + 32 * c) * 68 + k);
#pragma unroll
                    for (int r = 0; r < 8; ++r) {
                        accA[r][c] += ar4[r].x * ac4.x + ar4[r].y * ac4.y + ar4[r].z * ac4.z + ar4[r].w * ac4.w;
                        accB[r][c] += br4[r].x * bc4.x + br4[r].y * bc4.y + br4[r].z * bc4.z + br4[r].w * bc4.w;
                    }
                }
            }
        }
#pragma unroll
        for (int tens = 0; tens < 2; ++tens) {
            __syncthreads();
            scr[q * 64 + cc]        = tens ? cSB[0] : cSA[0];
            scr[512 + q * 64 + cc]  = tens ? cSB[1] : cSA[1];
            scr[1024 + q * 64 + cc] = tens ? cQB[0] : cQA[0];
            scr[1536 + q * 64 + cc] = tens ? cQB[1] : cQA[1];
            __syncthreads();
            if (tid < 128) {
                int st = tid >> 6, c2 = tid & 63;
                float s = 0.f, qq = 0.f;
#pragma unroll
                for (int g = 0; g < 8; ++g) {
                    s  += scr[st * 512 + g * 64 + c2];
                    qq += scr[1024 + st * 512 + g * 64 + c2];
                }
                int col = chunk * 128 + st * 64 + c2;
                float* C = ws + COLS_OFF + tens * 2 * DIM;
                C[col] = s; C[DIM + col] = qq;
            }
        }
        for (int o = 32; o; o >>= 1) mse += __shfl_xor(mse, o);
        if ((tid & 63) == 0) atomicAdd(&ws[WS_MSE], mse);
        if (RED) {
            float* P = ws + GK2PART_OFF + (size_t)chunk * 32768;
#pragma unroll
            for (int r = 0; r < 8; ++r)
#pragma unroll
                for (int c = 0; c < 4; ++c) {
                    P[(ty + 16 * r) * 128 + tx + 32 * c] = accA[r][c];
                    P[16384 + (ty + 16 * r) * 128 + tx + 32 * c] = accB[r][c];
                }
        } else {
#pragma unroll
            for (int r = 0; r < 8; ++r)
#pragma unroll
                for (int c = 0; c < 4; ++c) {
                    atomicAdd(&ws[GRAMA_OFF + (ty + 16 * r) * 128 + tx + 32 * c], accA[r][c]);
                    atomicAdd(&ws[GRAMB_OFF + (ty + 16 * r) * 128 + tx + 32 * c], accB[r][c]);
                }
        }
        __syncthreads();    // all shm reads done before l1 staging overwrites
    }

    // ================= L1 role (ALL 256 blocks) =================
    {
        const int lb = blockIdx.x;                 // 0..255
        unsigned char* buf0 = shm;                 // 2 x 50176B bf16 buffers
        unsigned char* buf1 = shm + 50176;
        const int wv = tid >> 6, lane = tid & 63;
        const int fr = lane & 15, kg = lane >> 4;
        const int batch = lb >> 1;
        const int kh    = lb & 1;
        const float* Az = za_l + (size_t)batch * HW * DIM + (size_t)kh * 4096;
        const float* Bz = zb_l + (size_t)batch * HW * DIM + (size_t)kh * 4096;

        // row-units: u = wv + 8i (98 units: A rows 0-48, B rows 49-97).
        // ONE WAVE loads ONE unit = 1KB contiguous (lane*16B). waves 0,1: 13
        // units; waves 2-7: 12 — vmcnt immediates match per wave.
        const float* gp[13];
        int wb[13];
#pragma unroll
        for (int i = 0; i < 13; ++i) {
            int u = wv + 8 * i;
            gp[i] = Az; wb[i] = -1;
            if (u < 98) {
                const float* rbase = (u < 49) ? (Az + (size_t)u * DIM)
                                              : (Bz + (size_t)(u - 49) * DIM);
                gp[i] = rbase + lane * 4;
                // bf16 row = 512B; lane's 4 floats -> 8B at 16B-slot lane>>1,
                // half lane&1; slot swizzled by row&15
                wb[i] = u * 512 + ((((lane >> 1) ^ (u & 15)) << 4) | ((lane & 1) << 3));
            }
        }

        // fragment bases (A rows 0-48; B rows 49-97), bf16 rows of 512B
        const int wr = wv >> 2, wc = wv & 3;
        int ar0 = wr * 32 + fr;                       // <= 47
        int ar1 = ar0 + 16; if (ar1 > 48) ar1 = 48;   // clamp pad rows
        int bc  = wc * 16 + fr; if (bc > 48) bc = 48;
        const int brow = 49 + bc;
        const int aw0 = ar0 << 9, pa0 = ar0 & 15;
        const int aw1 = ar1 << 9, pa1 = ar1 & 15;
        const int bw  = brow << 9, pb = brow & 15;

        f32x4 acc00 = {0.f,0.f,0.f,0.f}, acc10 = {0.f,0.f,0.f,0.f};
        f32x4 aa0 = {0.f,0.f,0.f,0.f}, aa1 = {0.f,0.f,0.f,0.f}, bb = {0.f,0.f,0.f,0.f};

        f32x4 RS0[13], RS1[13];

#define GLOAD(dst, i, s) do {                                                  \
        if (wb[i] >= 0) {                                                      \
            const float* p_ = gp[i] + (size_t)(s) * 256;                       \
            asm volatile("global_load_dwordx4 %0, %1, off"                     \
                         : "=v"(dst) : "v"(p_) : "memory");                    \
        } } while (0)

#define L1_LOADS(RS, s) do {                                                   \
        GLOAD(RS[0], 0, s);  GLOAD(RS[1], 1, s);  GLOAD(RS[2], 2, s);          \
        GLOAD(RS[3], 3, s);  GLOAD(RS[4], 4, s);  GLOAD(RS[5], 5, s);          \
        GLOAD(RS[6], 6, s);  GLOAD(RS[7], 7, s);  GLOAD(RS[8], 8, s);          \
        GLOAD(RS[9], 9, s);  GLOAD(RS[10], 10, s); GLOAD(RS[11], 11, s);       \
        GLOAD(RS[12], 12, s); } while (0)

#define L1_CVTWRITE(RS, B) do {                                                \
        _Pragma("unroll") for (int i = 0; i < 13; ++i)                         \
            if (wb[i] >= 0) {                                                  \
                f32x4 v_ = RS[i];                                              \
                *(uint2*)((B) + wb[i]) =                                       \
                    make_uint2(cvtpk(v_.x, v_.y), cvtpk(v_.z, v_.w));          \
            } } while (0)

#define L1_COMPUTE(B) do {                                                     \
        _Pragma("unroll") for (int kk = 0; kk < 8; ++kk) {                     \
            const int s0_ = kk * 4 + kg;                                       \
            bf16x8 a0 = *(const bf16x8*)((B) + aw0 + (((s0_) ^ pa0) << 4));    \
            bf16x8 a1 = *(const bf16x8*)((B) + aw1 + (((s0_) ^ pa1) << 4));    \
            bf16x8 b0 = *(const bf16x8*)((B) + bw  + (((s0_) ^ pb ) << 4));    \
            acc00 = __builtin_amdgcn_mfma_f32_16x16x32_bf16(a0, b0, acc00, 0, 0, 0); \
            acc10 = __builtin_amdgcn_mfma_f32_16x16x32_bf16(a1, b0, acc10, 0, 0, 0); \
            aa0   = __builtin_amdgcn_mfma_f32_16x16x32_bf16(a0, a0, aa0,   0, 0, 0); \
            aa1   = __builtin_amdgcn_mfma_f32_16x16x32_bf16(a1, a1, aa1,   0, 0, 0); \
            bb    = __builtin_amdgcn_mfma_f32_16x16x32_bf16(b0, b0, bb,    0, 0, 0); \
        } } while (0)

#define VMWAIT_STEADY() do {                                                   \
        if (wv < 2) asm volatile("s_waitcnt vmcnt(13)" ::: "memory");          \
        else        asm volatile("s_waitcnt vmcnt(12)" ::: "memory");          \
        } while (0)

        // clean counter after gk2 prologue (its loads/stores count in vmcnt)
        asm volatile("s_waitcnt vmcnt(0)" ::: "memory");
        SB0();

        L1_LOADS(RS0, 0); SB0();
        L1_LOADS(RS1, 1); SB0();

#pragma unroll 1
        for (int s = 0; s < 16; s += 2) {
            // ---- even stage s -> buf0 ----
            VMWAIT_STEADY(); SB0();                  // stage s arrived; s+1 airborne
            L1_CVTWRITE(RS0, buf0);
            asm volatile("s_waitcnt lgkmcnt(0)" ::: "memory"); SB0();
            __builtin_amdgcn_s_barrier(); SB0();     // buf0 complete; compute(s-1) done
            if (s + 2 < 16) { L1_LOADS(RS0, s + 2); SB0(); }
            L1_COMPUTE(buf0);
            // ---- odd stage s+1 -> buf1 ----
            if (s + 1 == 15) asm volatile("s_waitcnt vmcnt(0)" ::: "memory");
            else             VMWAIT_STEADY();
            SB0();
            L1_CVTWRITE(RS1, buf1);
            asm volatile("s_waitcnt lgkmcnt(0)" ::: "memory"); SB0();
            __builtin_amdgcn_s_barrier(); SB0();
            if (s + 3 < 16) { L1_LOADS(RS1, s + 3); SB0(); }
            L1_COMPUTE(buf1);
        }
#undef GLOAD
#undef L1_LOADS
#undef L1_CVTWRITE
#undef L1_COMPUTE
#undef VMWAIT_STEADY

        // epilogue: disjoint stores (RED) / atomics (fallback)
        float* gout = l1part + (size_t)(RED ? lb : batch) * SLOT;
        const int gc = wc * 16 + fr;
#pragma unroll
        for (int rr = 0; rr < 4; ++rr) {
            int gr0 = wr * 32 + kg * 4 + rr;
            int gr1 = gr0 + 16;
            if (gc < HW) {
                if (gr0 < HW) {
                    if (RED) gout[gr0 * HW + gc] = acc00[rr];
                    else atomicAdd(&gout[gr0 * HW + gc], acc00[rr]);
                }
                if (gr1 < HW) {
                    if (RED) gout[gr1 * HW + gc] = acc10[rr];
                    else atomicAdd(&gout[gr1 * HW + gc], acc10[rr]);
                }
            }
        }
        // norms from Gram diagonals: C/D col=fr, row=kg*4+rr -> diag at fr==i
        if (wc == 0) {
#pragma unroll
            for (int rr = 0; rr < 4; ++rr) {
                int i = kg * 4 + rr;
                if (i == fr) {
                    int r0 = wr * 32 + i;
                    if (RED) gout[PAIRS + r0] = aa0[rr];
                    else atomicAdd(&gout[PAIRS + r0], aa0[rr]);
                    int r1 = r0 + 16;
                    if (r1 < HW) {
                        if (RED) gout[PAIRS + r1] = aa1[rr];
                        else atomicAdd(&gout[PAIRS + r1], aa1[rr]);
                    }
                }
            }
        }
        if (wr == 0) {
#pragma unroll
            for (int rr = 0; rr < 4; ++rr) {
                int i = kg * 4 + rr;
                if (i == fr) {
                    int rb_ = wc * 16 + i;
                    if (rb_ < HW) {
                        if (RED) gout[PAIRS + HW + rb_] = bb[rr];
                        else atomicAdd(&gout[PAIRS + HW + rb_], bb[rr]);
                    }
                }
            }
        }
    }
}

// ---------------------------------------------------------------------------
// MERGE2: blocks 0-127 gk2_reduce; 128-159 gk1b; 160-287 l2_match.
// ---------------------------------------------------------------------------
template<bool RED>
__global__ __launch_bounds__(256) void merge2(const float* __restrict__ ga,
                                              const float* __restrict__ gb,
                                              float* __restrict__ ws,
                                              const float* __restrict__ l1part)
{
    __shared__ float d2f[PAIRS];
    __shared__ float d2g[PAIRS];
    __shared__ float nAs[49], nBs[49];
    __shared__ float gax[49], gay[49], gbx[49], gby[49];
    __shared__ float mval[4][49];
    __shared__ int   midx[4][49];

    const int b = blockIdx.x;
    const int tid = threadIdx.x;

    if (b < 128) {
        if (!RED) return;
        int gid = b * 256 + tid;                 // 0..32767
        int tensor = gid >> 14, e = gid & 16383;
        const float* P = ws + GK2PART_OFF + (size_t)tensor * 16384;
        float s = 0.f;
        for (int c = 0; c < 64; ++c) s += P[(size_t)c * 32768 + e];
        ws[(tensor ? GRAMB_OFF : GRAMA_OFF) + e] = s;
        return;
    }
    if (b < 160) {
        int col = (b - 128) * 256 + tid;
        float sa = ws[COLS_OFF + col];
        float qa = ws[COLS_OFF + DIM + col];
        float sb = ws[COLS_OFF + 2 * DIM + col];
        float qb = ws[COLS_OFF + 3 * DIM + col];
        float sA = qa - sa * sa * (1.0f / BATCH);
        float sB = qb - sb * sb * (1.0f / BATCH);
        float rA = fmaxf(0.f, 1.f - sqrtf(sA * (1.0f / (BATCH - 1)) + 1e-4f));
        float rB = fmaxf(0.f, 1.f - sqrtf(sB * (1.0f / (BATCH - 1)) + 1e-4f));
        float dA = sA * sA, dB = sB * sB;
        for (int o = 32; o; o >>= 1) {
            rA += __shfl_xor(rA, o);
            rB += __shfl_xor(rB, o);
            dA += __shfl_xor(dA, o);
            dB += __shfl_xor(dB, o);
        }
        if ((tid & 63) == 0) {
            atomicAdd(&ws[WS_VARA],  rA);
            atomicAdd(&ws[WS_VARB],  rB);
            atomicAdd(&ws[WS_DIAGA], dA);
            atomicAdd(&ws[WS_DIAGB], dB);
        }
        return;
    }

    // l2_match role
    const int batch = b - 160;
    const float* P0 = l1part + (size_t)batch * (RED ? (2 * SLOT) : SLOT);
    auto rd = [&](int off) -> float {
        if (!RED) return P0[off];
        return P0[off] + P0[SLOT + off];
    };

    if (tid < 49) nAs[tid] = rd(PAIRS + tid);
    else if (tid >= 64 && tid < 113) nBs[tid - 64] = rd(PAIRS + 49 + (tid - 64));
    if (tid >= 128 && tid < 177) {
        int i = tid - 128;
        gax[i] = ga[batch * 98 + i * 2];
        gay[i] = ga[batch * 98 + i * 2 + 1];
    } else if (tid >= 192 && tid < 241) {
        int i = tid - 192;
        gbx[i] = gb[batch * 98 + i * 2];
        gby[i] = gb[batch * 98 + i * 2 + 1];
    }
    __syncthreads();
    for (int e = tid; e < PAIRS; e += 256) {
        int i = e / 49, j = e - i * 49;
        d2f[e] = nAs[i] + nBs[j] - 2.0f * rd(e);
        float dx = gax[i] - gbx[j], dy = gay[i] - gby[j];
        d2g[e] = dx * dx + dy * dy;
    }
    __syncthreads();
    const int task = tid >> 6, l = tid & 63;
    if (l < 49) {
        float bv = 3.0e38f; int bi = 0;
        if (task == 0) {
            for (int j = 0; j < 49; ++j) { float v = d2f[l * 49 + j]; if (v < bv) { bv = v; bi = j; } }
        } else if (task == 1) {
            for (int i = 0; i < 49; ++i) { float v = d2f[i * 49 + l]; if (v < bv) { bv = v; bi = i; } }
        } else if (task == 2) {
            for (int j = 0; j < 49; ++j) { float v = d2g[l * 49 + j]; if (v < bv) { bv = v; bi = j; } }
        } else {
            for (int i = 0; i < 49; ++i) { float v = d2g[i * 49 + l]; if (v < bv) { bv = v; bi = i; } }
        }
        mval[task][l] = bv; midx[task][l] = bi;
    }
    __syncthreads();
    if (l < 49) {
        float v = mval[task][l];
        int rank = 0;
        for (int k = 0; k < 49; ++k) {
            float u = mval[task][k];
            rank += (u < v) || (u == v && k < l);   // stable: matches lax.top_k ties
        }
        if (task == 0)      { if (rank < 20) atomicAdd(&ws[WS_S1], v); }
        else if (task == 1) { if (rank < 20) atomicAdd(&ws[WS_S2], v); }
        else if (task == 2) { if (rank < 20) atomicAdd(&ws[WS_S3], d2f[l * 49 + midx[2][l]]); }
        else                { if (rank < 4)  atomicAdd(&ws[WS_S4], d2f[midx[3][l] * 49 + l]); }
    }
}

// ---------------------------------------------------------------------------
// GK3+GK4: ||K||_F^2 per tensor (2 blocks); the LAST finisher (device-scope
// ticket) assembles the final scalar.
// ---------------------------------------------------------------------------
__global__ __launch_bounds__(256) void gk3_final(float* __restrict__ ws,
                                                 float* __restrict__ out)
{
    __shared__ float r[128];
    __shared__ float sS;
    __shared__ float wrd[4];
    const int tid = threadIdx.x;
    const float* G = ws + (blockIdx.x ? GRAMB_OFF : GRAMA_OFF);
    if (tid < 128) {
        float s0 = 0.f, s1 = 0.f, s2 = 0.f, s3 = 0.f;
        for (int k = 0; k < 128; k += 4) {
            s0 += G[(k + 0) * 128 + tid];
            s1 += G[(k + 1) * 128 + tid];
            s2 += G[(k + 2) * 128 + tid];
            s3 += G[(k + 3) * 128 + tid];
        }
        r[tid] = (s0 + s1) + (s2 + s3);
    }
    __syncthreads();
    if (tid < 64) {
        float t = r[tid] + r[tid + 64];
        for (int o = 32; o; o >>= 1) t += __shfl_xor(t, o);
        if (tid == 0) sS = t;
    }
    __syncthreads();
    const float S = sS;
    float sk = 0.f;
    for (int e = tid; e < 16384; e += 256) {
        float K = G[e] - (r[e >> 7] + r[e & 127]) * (1.0f / 128.0f) + S * (1.0f / 16384.0f);
        sk += K * K;
    }
    for (int o = 32; o; o >>= 1) sk += __shfl_xor(sk, o);
    if ((tid & 63) == 0) wrd[tid >> 6] = sk;
    __syncthreads();
    if (tid == 0) {
        ws[blockIdx.x ? WS_SK2B : WS_SK2A] = wrd[0] + wrd[1] + wrd[2] + wrd[3];
        __threadfence();
        unsigned t = atomicAdd((unsigned*)&ws[WS_TICKET], 1u);
        if (t == 1) {            // last of the 2 blocks: assemble final scalar
            __threadfence();
            float inv_g = ws[WS_MSE] * (1.0f / ((float)BATCH * (float)DIM));
            float varl  = 0.5f * (ws[WS_VARA] + ws[WS_VARB]) * (1.0f / (float)DIM);
            float cov   = (ws[WS_SK2A] - ws[WS_DIAGA] + ws[WS_SK2B] - ws[WS_DIAGB])
                          * (1.0f / (127.0f * 127.0f * (float)DIM));
            float gl = 25.0f * inv_g + 25.0f * varl + cov;
            float m20 = (float)BATCH * 20.0f * (float)DIM;
            float m4  = (float)BATCH * 4.0f  * (float)DIM;
            float invl = 0.5f * (ws[WS_S1] + ws[WS_S2] + ws[WS_S3]) / m20
                       + 0.5f * ws[WS_S4] / m4;
            out[0] = 0.25f * gl + 0.75f * (25.0f * invl);
        }
    }
}

extern "C" void kernel_launch(void* const* d_in, const int* in_sizes, int n_in,
                              void* d_out, int out_size, void* d_ws, size_t ws_size,
                              hipStream_t stream)
{
    (void)in_sizes; (void)n_in; (void)out_size;
    const float* z_a = (const float*)d_in[0];
    const float* z_b = (const float*)d_in[1];
    const float* zla = (const float*)d_in[2];
    const float* zlb = (const float*)d_in[3];
    const float* ga  = (const float*)d_in[4];
    const float* gb  = (const float*)d_in[5];
    float* ws  = (float*)d_ws;
    float* out = (float*)d_out;

    const bool big = ws_size >= (size_t)WS_NEED_FLOATS * sizeof(float);

    if (big) {
        hipMemsetAsync(d_ws, 0, 16 * sizeof(float), stream);
        uber<true><<<256, 512, 0, stream>>>(zla, zlb, z_a, z_b, ws, ws + L1PART_BIG);
        merge2<true><<<288, 256, 0, stream>>>(ga, gb, ws, ws + L1PART_BIG);
        gk3_final<<<2, 256, 0, stream>>>(ws, out);
    } else {
        hipMemsetAsync(d_ws, 0, (size_t)(L1PART_SMALL + BATCH * SLOT) * sizeof(float), stream);
        uber<false><<<256, 512, 0, stream>>>(zla, zlb, z_a, z_b, ws, ws + L1PART_SMALL);
        merge2<false><<<288, 256, 0, stream>>>(ga, gb, ws, ws + L1PART_SMALL);
        gk3_final<<<2, 256, 0, stream>>>(ws, out);
    }
}

// Round 15
// 116.975 us; speedup vs baseline: 1.0723x; 1.0723x over previous
//
#include <hip/hip_runtime.h>
#include <math.h>

#define BATCH 128
#define DIM   8192
#define HW    49
#define PAIRS 2401            // 49*49
#define SLOT  2512            // per-partial slot: 2401 G + 49 nA + 49 nB + pad

// ws float offsets
#define WS_MSE    0
#define WS_VARA   1
#define WS_VARB   2
#define WS_DIAGA  3
#define WS_DIAGB  4
#define WS_S1     5
#define WS_S2     6
#define WS_S3     7
#define WS_S4     8
#define WS_SK2A   9
#define WS_SK2B   10
#define WS_TICKET 11
#define COLS_OFF    16                         // saA,qaA,sbB,qbB: 4*DIM
#define GRAMA_OFF   32784
#define GRAMB_OFF   49168
#define GK2PART_OFF 65552                      // 64 chunks * 32768 (A then B)
#define L1PART_BIG  2162704                    // 512 slots * SLOT
#define WS_NEED_FLOATS (L1PART_BIG + 512 * SLOT)    // ~13.8 MB (R8-proven fit)
#define L1PART_SMALL 65552                     // fallback: 128 batch slots (atomic)

typedef __attribute__((ext_vector_type(8))) short bf16x8;
typedef __attribute__((ext_vector_type(4))) float f32x4;

__device__ __forceinline__ unsigned cvtpk(float lo, float hi) {
    unsigned r;
    asm("v_cvt_pk_bf16_f32 %0, %1, %2" : "=v"(r) : "v"(lo), "v"(hi));
    return r;
}

#define SB0() __builtin_amdgcn_sched_barrier(0)

// ---------------------------------------------------------------------------
// UBER kernel, 512 threads, grid = 576. Static LDS = 50176B -> TWO l1 blocks
// per CU (16 waves): when one block's waves sit in cvt/write/barrier/compute,
// the co-resident block keeps the CU's memory queues fed (the occupancy lever
// every round since R8 structurally excluded at >=80KB LDS; m13's 10.2 B/cyc
// reference runs 8 blocks/CU vs our 5.8 at 1 block/CU).
//  blocks 0..63   : GK2 role, <=43KB LDS — 128x128 Grams of z_a,z_b via two
//    64-col sub-chunks (one tensor staged at a time), col sum/sumsq, global
//    MSE via L2-hot re-read. Rides as a 3rd block on 64 CUs (150KB, 1536thr).
//  blocks 64..575 : L1 role — R13's proven structure verbatim: per-batch
//    padded 64x64 Gram of 49x8192 features, 128 batches x 4 K-splits
//    (K=2048, 16 stages of BK=128), manual inline-asm global_load_dwordx4,
//    2 register sets in flight, per-wave counted vmcnt(7/6), cvt->bf16,
//    swizzled ds_write into 2 x 24.5KB bf16 buffers, raw s_barrier.
// ---------------------------------------------------------------------------
template<bool RED>
__global__ __launch_bounds__(512) void uber(const float* __restrict__ za_l,
                                            const float* __restrict__ zb_l,
                                            const float* __restrict__ z_a,
                                            const float* __restrict__ z_b,
                                            float* __restrict__ ws,
                                            float* __restrict__ l1part)
{
    __shared__ __align__(16) unsigned char shm[50176];
    const int tid = threadIdx.x;

    if (blockIdx.x < 64) {
        // ================= GK2 role (43KB LDS) =================
        const int chunk = blockIdx.x;              // 128-col chunk
        float* sx  = (float*)shm;                  // 128 x 68 fp32 = 34816B
        float* scr = sx + 128 * 68;                // 1024 floats = 4KB
        const int ty = tid >> 5, tx = tid & 31;
        const int q = tid >> 6, cc = tid & 63;

        float accA[2][8][4], accB[2][8][4];        // [st][r][c] per tensor? no:
        // acc[t][r][c] summed over both st; use two named arrays (static idx)
#pragma unroll
        for (int r = 0; r < 8; ++r)
#pragma unroll
            for (int c = 0; c < 4; ++c) {
                accA[0][r][c] = 0.f; accB[0][r][c] = 0.f;
                accA[1][r][c] = 0.f; accB[1][r][c] = 0.f;   // unused halves kept zero
            }
        float cS[2][2], cQ[2][2];                  // [tensor][st]
        cS[0][0]=cS[0][1]=cS[1][0]=cS[1][1]=0.f;
        cQ[0][0]=cQ[0][1]=cQ[1][0]=cQ[1][1]=0.f;

#pragma unroll
        for (int st = 0; st < 2; ++st) {
#pragma unroll
            for (int tens = 0; tens < 2; ++tens) {
                const float* X = tens ? z_b : z_a;
                __syncthreads();
                for (int f = tid; f < 2048; f += 512) {   // 128 rows x 16 f4
                    int row = f >> 4, c4 = f & 15;
                    *(float4*)(sx + row * 68 + c4 * 4) =
                        *(const float4*)(X + (size_t)row * DIM + chunk * 128 + st * 64 + c4 * 4);
                }
                __syncthreads();
                // col stats: col cc, rows q*16..+16
                {
                    float s = 0.f, qq = 0.f;
                    for (int r = 0; r < 16; ++r) {
                        float v = sx[(q * 16 + r) * 68 + cc];
                        s += v; qq += v * v;
                    }
                    cS[tens][st] += s; cQ[tens][st] += qq;
                }
                // symmetric gram over this 64-col slab
                for (int k = 0; k < 64; k += 4) {
                    float4 r4[8];
#pragma unroll
                    for (int r = 0; r < 8; ++r)
                        r4[r] = *(const float4*)(sx + (ty + 16 * r) * 68 + k);
#pragma unroll
                    for (int c = 0; c < 4; ++c) {
                        float4 c4v = *(const float4*)(sx + (tx + 32 * c) * 68 + k);
#pragma unroll
                        for (int r = 0; r < 8; ++r) {
                            float d = r4[r].x * c4v.x + r4[r].y * c4v.y
                                    + r4[r].z * c4v.z + r4[r].w * c4v.w;
                            if (tens) accB[0][r][c] += d; else accA[0][r][c] += d;
                        }
                    }
                }
            }
        }
        // col-stat reduce: 4 rounds via scr
#pragma unroll
        for (int tens = 0; tens < 2; ++tens)
#pragma unroll
            for (int st = 0; st < 2; ++st) {
                __syncthreads();
                scr[q * 64 + cc]       = cS[tens][st];
                scr[512 + q * 64 + cc] = cQ[tens][st];
                __syncthreads();
                if (tid < 64) {
                    float s = 0.f, qq = 0.f;
#pragma unroll
                    for (int g = 0; g < 8; ++g) {
                        s  += scr[g * 64 + tid];
                        qq += scr[512 + g * 64 + tid];
                    }
                    int col = chunk * 128 + st * 64 + tid;
                    float* C = ws + COLS_OFF + tens * 2 * DIM;
                    C[col] = s; C[DIM + col] = qq;
                }
            }
        // global MSE for this 128-col slab (L2-hot re-read)
        {
            float mse = 0.f;
            for (int f = tid; f < 4096; f += 512) {       // 128 rows x 32 f4
                int row = f >> 5, c4 = f & 31;
                size_t idx = (size_t)row * DIM + chunk * 128 + c4 * 4;
                float4 a4 = *(const float4*)(z_a + idx);
                float4 b4 = *(const float4*)(z_b + idx);
                float dx = a4.x - b4.x, dy = a4.y - b4.y, dz = a4.z - b4.z, dw = a4.w - b4.w;
                mse += dx * dx + dy * dy + dz * dz + dw * dw;
            }
            for (int o = 32; o; o >>= 1) mse += __shfl_xor(mse, o);
            if ((tid & 63) == 0) atomicAdd(&ws[WS_MSE], mse);
        }
        // Gram out
        if (RED) {
            float* P = ws + GK2PART_OFF + (size_t)chunk * 32768;
#pragma unroll
            for (int r = 0; r < 8; ++r)
#pragma unroll
                for (int c = 0; c < 4; ++c) {
                    P[(ty + 16 * r) * 128 + tx + 32 * c] = accA[0][r][c];
                    P[16384 + (ty + 16 * r) * 128 + tx + 32 * c] = accB[0][r][c];
                }
        } else {
#pragma unroll
            for (int r = 0; r < 8; ++r)
#pragma unroll
                for (int c = 0; c < 4; ++c) {
                    atomicAdd(&ws[GRAMA_OFF + (ty + 16 * r) * 128 + tx + 32 * c], accA[0][r][c]);
                    atomicAdd(&ws[GRAMB_OFF + (ty + 16 * r) * 128 + tx + 32 * c], accB[0][r][c]);
                }
        }
        return;
    }

    // ================= L1 role (512 blocks, 2/CU) =================
    {
        const int lb = blockIdx.x - 64;            // 0..511
        unsigned char* buf0 = shm;                 // 2 x 25088B bf16 buffers
        unsigned char* buf1 = shm + 25088;
        const int wv = tid >> 6, lane = tid & 63;
        const int fr = lane & 15, kg = lane >> 4;
        const int batch = lb >> 2;
        const int ks    = lb & 3;
        const float* Az = za_l + (size_t)batch * HW * DIM + (size_t)ks * 2048;
        const float* Bz = zb_l + (size_t)batch * HW * DIM + (size_t)ks * 2048;

        // pair-unit j = wv + 8i covers rows 2j (lanes 0-31), 2j+1 (lanes 32-63)
        const int half = lane >> 5, l5 = lane & 31;
        const float* gp[7];
        int wb[7];
#pragma unroll
        for (int i = 0; i < 7; ++i) {
            int j = wv + 8 * i;
            gp[i] = Az; wb[i] = -1;
            if (j < 49) {
                int row = 2 * j + half;
                const float* rbase = (row < 49) ? (Az + (size_t)row * DIM)
                                                : (Bz + (size_t)(row - 49) * DIM);
                gp[i] = rbase + l5 * 4;
                // bf16 row = 256B; 16B slot (l5>>1)^(row&15), 8B half (l5&1)
                wb[i] = row * 256 + ((((l5 >> 1) ^ (row & 15)) << 4) | ((l5 & 1) << 3));
            }
        }

        // fragment bases (A rows 0-48; B rows 49-97), bf16 rows of 256B
        const int wr = wv >> 2, wc = wv & 3;
        int ar0 = wr * 32 + fr;                       // <= 47
        int ar1 = ar0 + 16; if (ar1 > 48) ar1 = 48;   // clamp pad rows
        int bc  = wc * 16 + fr; if (bc > 48) bc = 48;
        const int brow = 49 + bc;
        const int aw0 = ar0 << 8, pa0 = ar0 & 15;
        const int aw1 = ar1 << 8, pa1 = ar1 & 15;
        const int bw  = brow << 8, pb = brow & 15;

        f32x4 acc00 = {0.f,0.f,0.f,0.f}, acc10 = {0.f,0.f,0.f,0.f};
        f32x4 aa0 = {0.f,0.f,0.f,0.f}, aa1 = {0.f,0.f,0.f,0.f}, bb = {0.f,0.f,0.f,0.f};

        f32x4 RS0[7], RS1[7];

#define GLOAD(dst, i, s) do {                                                  \
        if (wb[i] >= 0) {                                                      \
            const float* p_ = gp[i] + (size_t)(s) * 128;                       \
            asm volatile("global_load_dwordx4 %0, %1, off"                     \
                         : "=v"(dst) : "v"(p_) : "memory");                    \
        } } while (0)

#define L1_LOADS(RS, s) do {                                                   \
        GLOAD(RS[0], 0, s); GLOAD(RS[1], 1, s); GLOAD(RS[2], 2, s);            \
        GLOAD(RS[3], 3, s); GLOAD(RS[4], 4, s); GLOAD(RS[5], 5, s);            \
        GLOAD(RS[6], 6, s); } while (0)

#define L1_CVTWRITE(RS, B) do {                                                \
        _Pragma("unroll") for (int i = 0; i < 7; ++i)                          \
            if (wb[i] >= 0) {                                                  \
                f32x4 v_ = RS[i];                                              \
                *(uint2*)((B) + wb[i]) =                                       \
                    make_uint2(cvtpk(v_.x, v_.y), cvtpk(v_.z, v_.w));          \
            } } while (0)

#define L1_COMPUTE(B) do {                                                     \
        _Pragma("unroll") for (int kk = 0; kk < 4; ++kk) {                     \
            const int s0_ = kk * 4 + kg;                                       \
            bf16x8 a0 = *(const bf16x8*)((B) + aw0 + (((s0_) ^ pa0) << 4));    \
            bf16x8 a1 = *(const bf16x8*)((B) + aw1 + (((s0_) ^ pa1) << 4));    \
            bf16x8 b0 = *(const bf16x8*)((B) + bw  + (((s0_) ^ pb ) << 4));    \
            acc00 = __builtin_amdgcn_mfma_f32_16x16x32_bf16(a0, b0, acc00, 0, 0, 0); \
            acc10 = __builtin_amdgcn_mfma_f32_16x16x32_bf16(a1, b0, acc10, 0, 0, 0); \
            aa0   = __builtin_amdgcn_mfma_f32_16x16x32_bf16(a0, a0, aa0,   0, 0, 0); \
            aa1   = __builtin_amdgcn_mfma_f32_16x16x32_bf16(a1, a1, aa1,   0, 0, 0); \
            bb    = __builtin_amdgcn_mfma_f32_16x16x32_bf16(b0, b0, bb,    0, 0, 0); \
        } } while (0)

#define VMWAIT_STEADY() do {                                                   \
        if (wv == 0) asm volatile("s_waitcnt vmcnt(7)" ::: "memory");          \
        else         asm volatile("s_waitcnt vmcnt(6)" ::: "memory");          \
        } while (0)

        asm volatile("s_waitcnt vmcnt(0)" ::: "memory");
        SB0();

        L1_LOADS(RS0, 0); SB0();
        L1_LOADS(RS1, 1); SB0();

#pragma unroll 1
        for (int s = 0; s < 16; s += 2) {
            // ---- even stage s -> buf0 ----
            VMWAIT_STEADY(); SB0();                  // stage s arrived; s+1 airborne
            L1_CVTWRITE(RS0, buf0);
            asm volatile("s_waitcnt lgkmcnt(0)" ::: "memory"); SB0();
            __builtin_amdgcn_s_barrier(); SB0();     // buf0 complete; compute(s-1) done
            if (s + 2 < 16) { L1_LOADS(RS0, s + 2); SB0(); }
            L1_COMPUTE(buf0);
            // ---- odd stage s+1 -> buf1 ----
            if (s + 1 == 15) asm volatile("s_waitcnt vmcnt(0)" ::: "memory");
            else             VMWAIT_STEADY();
            SB0();
            L1_CVTWRITE(RS1, buf1);
            asm volatile("s_waitcnt lgkmcnt(0)" ::: "memory"); SB0();
            __builtin_amdgcn_s_barrier(); SB0();
            if (s + 3 < 16) { L1_LOADS(RS1, s + 3); SB0(); }
            L1_COMPUTE(buf1);
        }
#undef GLOAD
#undef L1_LOADS
#undef L1_CVTWRITE
#undef L1_COMPUTE
#undef VMWAIT_STEADY

        // epilogue: disjoint stores (RED) / atomics (fallback)
        float* gout = l1part + (size_t)(RED ? lb : batch) * SLOT;
        const int gc = wc * 16 + fr;
#pragma unroll
        for (int rr = 0; rr < 4; ++rr) {
            int gr0 = wr * 32 + kg * 4 + rr;
            int gr1 = gr0 + 16;
            if (gc < HW) {
                if (gr0 < HW) {
                    if (RED) gout[gr0 * HW + gc] = acc00[rr];
                    else atomicAdd(&gout[gr0 * HW + gc], acc00[rr]);
                }
                if (gr1 < HW) {
                    if (RED) gout[gr1 * HW + gc] = acc10[rr];
                    else atomicAdd(&gout[gr1 * HW + gc], acc10[rr]);
                }
            }
        }
        // norms from Gram diagonals: C/D col=fr, row=kg*4+rr -> diag at fr==i
        if (wc == 0) {
#pragma unroll
            for (int rr = 0; rr < 4; ++rr) {
                int i = kg * 4 + rr;
                if (i == fr) {
                    int r0 = wr * 32 + i;
                    if (RED) gout[PAIRS + r0] = aa0[rr];
                    else atomicAdd(&gout[PAIRS + r0], aa0[rr]);
                    int r1 = r0 + 16;
                    if (r1 < HW) {
                        if (RED) gout[PAIRS + r1] = aa1[rr];
                        else atomicAdd(&gout[PAIRS + r1], aa1[rr]);
                    }
                }
            }
        }
        if (wr == 0) {
#pragma unroll
            for (int rr = 0; rr < 4; ++rr) {
                int i = kg * 4 + rr;
                if (i == fr) {
                    int rb_ = wc * 16 + i;
                    if (rb_ < HW) {
                        if (RED) gout[PAIRS + HW + rb_] = bb[rr];
                        else atomicAdd(&gout[PAIRS + HW + rb_], bb[rr]);
                    }
                }
            }
        }
    }
}

// ---------------------------------------------------------------------------
// MERGE2: blocks 0-127 gk2_reduce; 128-159 gk1b; 160-287 l2_match (4 partials).
// ---------------------------------------------------------------------------
template<bool RED>
__global__ __launch_bounds__(256) void merge2(const float* __restrict__ ga,
                                              const float* __restrict__ gb,
                                              float* __restrict__ ws,
                                              const float* __restrict__ l1part)
{
    __shared__ float d2f[PAIRS];
    __shared__ float d2g[PAIRS];
    __shared__ float nAs[49], nBs[49];
    __shared__ float gax[49], gay[49], gbx[49], gby[49];
    __shared__ float mval[4][49];
    __shared__ int   midx[4][49];

    const int b = blockIdx.x;
    const int tid = threadIdx.x;

    if (b < 128) {
        if (!RED) return;
        int gid = b * 256 + tid;                 // 0..32767
        int tensor = gid >> 14, e = gid & 16383;
        const float* P = ws + GK2PART_OFF + (size_t)tensor * 16384;
        float s = 0.f;
        for (int c = 0; c < 64; ++c) s += P[(size_t)c * 32768 + e];
        ws[(tensor ? GRAMB_OFF : GRAMA_OFF) + e] = s;
        return;
    }
    if (b < 160) {
        int col = (b - 128) * 256 + tid;
        float sa = ws[COLS_OFF + col];
        float qa = ws[COLS_OFF + DIM + col];
        float sb = ws[COLS_OFF + 2 * DIM + col];
        float qb = ws[COLS_OFF + 3 * DIM + col];
        float sA = qa - sa * sa * (1.0f / BATCH);
        float sB = qb - sb * sb * (1.0f / BATCH);
        float rA = fmaxf(0.f, 1.f - sqrtf(sA * (1.0f / (BATCH - 1)) + 1e-4f));
        float rB = fmaxf(0.f, 1.f - sqrtf(sB * (1.0f / (BATCH - 1)) + 1e-4f));
        float dA = sA * sA, dB = sB * sB;
        for (int o = 32; o; o >>= 1) {
            rA += __shfl_xor(rA, o);
            rB += __shfl_xor(rB, o);
            dA += __shfl_xor(dA, o);
            dB += __shfl_xor(dB, o);
        }
        if ((tid & 63) == 0) {
            atomicAdd(&ws[WS_VARA],  rA);
            atomicAdd(&ws[WS_VARB],  rB);
            atomicAdd(&ws[WS_DIAGA], dA);
            atomicAdd(&ws[WS_DIAGB], dB);
        }
        return;
    }

    // l2_match role
    const int batch = b - 160;
    const float* P0 = l1part + (size_t)batch * (RED ? (4 * SLOT) : SLOT);
    auto rd = [&](int off) -> float {
        if (!RED) return P0[off];
        float s = 0.f;
#pragma unroll
        for (int ss = 0; ss < 4; ++ss) s += P0[ss * SLOT + off];
        return s;
    };

    if (tid < 49) nAs[tid] = rd(PAIRS + tid);
    else if (tid >= 64 && tid < 113) nBs[tid - 64] = rd(PAIRS + 49 + (tid - 64));
    if (tid >= 128 && tid < 177) {
        int i = tid - 128;
        gax[i] = ga[batch * 98 + i * 2];
        gay[i] = ga[batch * 98 + i * 2 + 1];
    } else if (tid >= 192 && tid < 241) {
        int i = tid - 192;
        gbx[i] = gb[batch * 98 + i * 2];
        gby[i] = gb[batch * 98 + i * 2 + 1];
    }
    __syncthreads();
    for (int e = tid; e < PAIRS; e += 256) {
        int i = e / 49, j = e - i * 49;
        d2f[e] = nAs[i] + nBs[j] - 2.0f * rd(e);
        float dx = gax[i] - gbx[j], dy = gay[i] - gby[j];
        d2g[e] = dx * dx + dy * dy;
    }
    __syncthreads();
    const int task = tid >> 6, l = tid & 63;
    if (l < 49) {
        float bv = 3.0e38f; int bi = 0;
        if (task == 0) {
            for (int j = 0; j < 49; ++j) { float v = d2f[l * 49 + j]; if (v < bv) { bv = v; bi = j; } }
        } else if (task == 1) {
            for (int i = 0; i < 49; ++i) { float v = d2f[i * 49 + l]; if (v < bv) { bv = v; bi = i; } }
        } else if (task == 2) {
            for (int j = 0; j < 49; ++j) { float v = d2g[l * 49 + j]; if (v < bv) { bv = v; bi = j; } }
        } else {
            for (int i = 0; i < 49; ++i) { float v = d2g[i * 49 + l]; if (v < bv) { bv = v; bi = i; } }
        }
        mval[task][l] = bv; midx[task][l] = bi;
    }
    __syncthreads();
    if (l < 49) {
        float v = mval[task][l];
        int rank = 0;
        for (int k = 0; k < 49; ++k) {
            float u = mval[task][k];
            rank += (u < v) || (u == v && k < l);   // stable: matches lax.top_k ties
        }
        if (task == 0)      { if (rank < 20) atomicAdd(&ws[WS_S1], v); }
        else if (task == 1) { if (rank < 20) atomicAdd(&ws[WS_S2], v); }
        else if (task == 2) { if (rank < 20) atomicAdd(&ws[WS_S3], d2f[l * 49 + midx[2][l]]); }
        else                { if (rank < 4)  atomicAdd(&ws[WS_S4], d2f[midx[3][l] * 49 + l]); }
    }
}

// ---------------------------------------------------------------------------
// GK3+GK4: ||K||_F^2 per tensor (2 blocks); the LAST finisher (device-scope
// ticket) assembles the final scalar.
// ---------------------------------------------------------------------------
__global__ __launch_bounds__(256) void gk3_final(float* __restrict__ ws,
                                                 float* __restrict__ out)
{
    __shared__ float r[128];
    __shared__ float sS;
    __shared__ float wrd[4];
    const int tid = threadIdx.x;
    const float* G = ws + (blockIdx.x ? GRAMB_OFF : GRAMA_OFF);
    if (tid < 128) {
        float s0 = 0.f, s1 = 0.f, s2 = 0.f, s3 = 0.f;
        for (int k = 0; k < 128; k += 4) {
            s0 += G[(k + 0) * 128 + tid];
            s1 += G[(k + 1) * 128 + tid];
            s2 += G[(k + 2) * 128 + tid];
            s3 += G[(k + 3) * 128 + tid];
        }
        r[tid] = (s0 + s1) + (s2 + s3);
    }
    __syncthreads();
    if (tid < 64) {
        float t = r[tid] + r[tid + 64];
        for (int o = 32; o; o >>= 1) t += __shfl_xor(t, o);
        if (tid == 0) sS = t;
    }
    __syncthreads();
    const float S = sS;
    float sk = 0.f;
    for (int e = tid; e < 16384; e += 256) {
        float K = G[e] - (r[e >> 7] + r[e & 127]) * (1.0f / 128.0f) + S * (1.0f / 16384.0f);
        sk += K * K;
    }
    for (int o = 32; o; o >>= 1) sk += __shfl_xor(sk, o);
    if ((tid & 63) == 0) wrd[tid >> 6] = sk;
    __syncthreads();
    if (tid == 0) {
        ws[blockIdx.x ? WS_SK2B : WS_SK2A] = wrd[0] + wrd[1] + wrd[2] + wrd[3];
        __threadfence();
        unsigned t = atomicAdd((unsigned*)&ws[WS_TICKET], 1u);
        if (t == 1) {            // last of the 2 blocks: assemble final scalar
            __threadfence();
            float inv_g = ws[WS_MSE] * (1.0f / ((float)BATCH * (float)DIM));
            float varl  = 0.5f * (ws[WS_VARA] + ws[WS_VARB]) * (1.0f / (float)DIM);
            float cov   = (ws[WS_SK2A] - ws[WS_DIAGA] + ws[WS_SK2B] - ws[WS_DIAGB])
                          * (1.0f / (127.0f * 127.0f * (float)DIM));
            float gl = 25.0f * inv_g + 25.0f * varl + cov;
            float m20 = (float)BATCH * 20.0f * (float)DIM;
            float m4  = (float)BATCH * 4.0f  * (float)DIM;
            float invl = 0.5f * (ws[WS_S1] + ws[WS_S2] + ws[WS_S3]) / m20
                       + 0.5f * ws[WS_S4] / m4;
            out[0] = 0.25f * gl + 0.75f * (25.0f * invl);
        }
    }
}

extern "C" void kernel_launch(void* const* d_in, const int* in_sizes, int n_in,
                              void* d_out, int out_size, void* d_ws, size_t ws_size,
                              hipStream_t stream)
{
    (void)in_sizes; (void)n_in; (void)out_size;
    const float* z_a = (const float*)d_in[0];
    const float* z_b = (const float*)d_in[1];
    const float* zla = (const float*)d_in[2];
    const float* zlb = (const float*)d_in[3];
    const float* ga  = (const float*)d_in[4];
    const float* gb  = (const float*)d_in[5];
    float* ws  = (float*)d_ws;
    float* out = (float*)d_out;

    const bool big = ws_size >= (size_t)WS_NEED_FLOATS * sizeof(float);

    if (big) {
        hipMemsetAsync(d_ws, 0, 16 * sizeof(float), stream);
        uber<true><<<576, 512, 0, stream>>>(zla, zlb, z_a, z_b, ws, ws + L1PART_BIG);
        merge2<true><<<288, 256, 0, stream>>>(ga, gb, ws, ws + L1PART_BIG);
        gk3_final<<<2, 256, 0, stream>>>(ws, out);
    } else {
        hipMemsetAsync(d_ws, 0, (size_t)(L1PART_SMALL + BATCH * SLOT) * sizeof(float), stream);
        uber<false><<<576, 512, 0, stream>>>(zla, zlb, z_a, z_b, ws, ws + L1PART_SMALL);
        merge2<false><<<288, 256, 0, stream>>>(ga, gb, ws, ws + L1PART_SMALL);
        gk3_final<<<2, 256, 0, stream>>>(ws, out);
    }
}